// Round 2
// baseline (1185.939 us; speedup 1.0000x reference)
//
#include <hip/hip_runtime.h>
#include <hip/hip_bf16.h>

#define NNODES 12288
#define NEDGES 393216
#define ETOT   (NEDGES + NNODES)
#define INCH   256
#define HIDC   128
#define NH     4
#define HC     512   // NH*HIDC
#define OUTC   64
#define SLOPE  0.2f

__device__ __forceinline__ float leaky(float v){ return v > 0.f ? v : SLOPE*v; }

__device__ __forceinline__ float wave_sum(float v){
#pragma unroll
  for (int m=32;m>0;m>>=1) v += __shfl_xor(v, m);
  return v;
}
__device__ __forceinline__ float wave_max(float v){
#pragma unroll
  for (int m=32;m>0;m>>=1) v = fmaxf(v, __shfl_xor(v, m));
  return v;
}

// ---- generic 64x64 tiled fp32 GEMM. M,Nc multiples of 64; K multiple of 16.
// EPI: 0 none, 1 +bias, 2 elu(x+bias), 3 sigmoid(x).  BT: B given as [Nc,K] (use B^T).
template<int EPI, bool BT>
__global__ __launch_bounds__(256) void gemm64(
    const float* __restrict__ A, const float* __restrict__ B,
    const float* __restrict__ bias, float* __restrict__ C,
    int M, int K, int Nc)
{
  __shared__ float As[16][68];
  __shared__ float Bs[16][68];
  int t = threadIdx.x;
  int tx = t & 15, ty = t >> 4;
  int m0 = blockIdx.y * 64, n0 = blockIdx.x * 64;
  float acc[4][4] = {};
  for (int k0 = 0; k0 < K; k0 += 16) {
    {  // A tile: 64 m x 16 k, float4 along k, scatter-transpose into LDS
      int m = t >> 2, kk = (t & 3) << 2;
      const float4 v = *(const float4*)&A[(size_t)(m0+m)*K + k0 + kk];
      As[kk+0][m] = v.x; As[kk+1][m] = v.y; As[kk+2][m] = v.z; As[kk+3][m] = v.w;
    }
    if (!BT) {
      int kk = t >> 4, nn = (t & 15) << 2;
      *(float4*)&Bs[kk][nn] = *(const float4*)&B[(size_t)(k0+kk)*Nc + n0 + nn];
    } else {
      int nn = t >> 2, kk = (t & 3) << 2;
      const float4 v = *(const float4*)&B[(size_t)(n0+nn)*K + k0 + kk];
      Bs[kk+0][nn] = v.x; Bs[kk+1][nn] = v.y; Bs[kk+2][nn] = v.z; Bs[kk+3][nn] = v.w;
    }
    __syncthreads();
#pragma unroll
    for (int kk = 0; kk < 16; ++kk) {
      float4 a = *(const float4*)&As[kk][ty<<2];
      float4 b = *(const float4*)&Bs[kk][tx<<2];
      float av[4]={a.x,a.y,a.z,a.w}, bv[4]={b.x,b.y,b.z,b.w};
#pragma unroll
      for (int i=0;i<4;++i)
#pragma unroll
        for (int j=0;j<4;++j) acc[i][j] += av[i]*bv[j];
    }
    __syncthreads();
  }
#pragma unroll
  for (int i=0;i<4;++i) {
    int row = m0 + (ty<<2) + i;
    int col = n0 + (tx<<2);
    float4 o; float* po = &o.x;
#pragma unroll
    for (int j=0;j<4;++j) {
      float v = acc[i][j];
      if (EPI==1) v += bias[col+j];
      if (EPI==2) { v += bias[col+j]; v = v>0.f ? v : (__expf(v)-1.f); }
      if (EPI==3) { v = 1.f/(1.f+__expf(-v)); }
      po[j]=v;
    }
    *(float4*)&C[(size_t)row*Nc + col] = o;
  }
}

// per-node per-head attention dots for layer 1: block = node, 4 waves = 4 heads
__global__ __launch_bounds__(256) void att1_kernel(
  const float* __restrict__ h1, const float* __restrict__ att_src,
  const float* __restrict__ att_dst, float* __restrict__ as1, float* __restrict__ ad1)
{
  int n = blockIdx.x; int t = threadIdx.x; int h = t>>6, lane = t&63;
  float2 v = *(const float2*)&h1[(size_t)n*HC + h*HIDC + lane*2];
  float2 a = *(const float2*)&att_src[h*HIDC + lane*2];
  float2 b = *(const float2*)&att_dst[h*HIDC + lane*2];
  float ps = wave_sum(v.x*a.x + v.y*a.y);
  float pd = wave_sum(v.x*b.x + v.y*b.y);
  if (lane==0){ as1[n*NH+h]=ps; ad1[n*NH+h]=pd; }
}

__global__ void zero_ints(int* p, int n){ int i=blockIdx.x*256+threadIdx.x; if(i<n) p[i]=0; }

__global__ void hist_kernel(const int* __restrict__ ei_dst, int* __restrict__ cnt){
  int e = blockIdx.x*256+threadIdx.x;
  if (e >= ETOT) return;
  int dst = e < NEDGES ? ei_dst[e] : e - NEDGES;
  atomicAdd(&cnt[dst], 1);
}

__global__ __launch_bounds__(1024) void scan_kernel(const int* __restrict__ cnt,
    int* __restrict__ rowptr, int* __restrict__ nxt){
  __shared__ int part[1024];
  int tid = threadIdx.x;
  int c[12]; int s=0;
  int base = tid*12;
#pragma unroll
  for (int j=0;j<12;++j){ c[j]=cnt[base+j]; s+=c[j]; }
  part[tid]=s; __syncthreads();
  for (int off=1; off<1024; off<<=1){
    int v=0; if (tid>=off) v=part[tid-off];
    __syncthreads();
    part[tid]+=v;
    __syncthreads();
  }
  int run = part[tid]-s;
#pragma unroll
  for (int j=0;j<12;++j){ rowptr[base+j]=run; nxt[base+j]=run; run+=c[j]; }
  if (tid==1023) rowptr[NNODES]=run;
}

__global__ void scatter_kernel(const int* __restrict__ ei_dst, int* __restrict__ nxt,
                               int* __restrict__ eids){
  int e = blockIdx.x*256+threadIdx.x;
  if (e >= ETOT) return;
  int dst = e < NEDGES ? ei_dst[e] : e - NEDGES;
  int pos = atomicAdd(&nxt[dst], 1);
  eids[pos] = e;
}

// layer-1 segment softmax + weighted aggregation. Block = dst node, 256 thr.
__global__ __launch_bounds__(256) void agg1_kernel(
  const float* __restrict__ h1, const float* __restrict__ as1, const float* __restrict__ ad1,
  const int* __restrict__ rowptr, const int* __restrict__ eids, const int* __restrict__ ei_src,
  const float* __restrict__ b1, float* __restrict__ out)
{
  __shared__ float4 red[256];
  int n = blockIdx.x; int t = threadIdx.x;
  int s0 = rowptr[n], s1 = rowptr[n+1];
  float ad[4];
#pragma unroll
  for (int h=0;h<4;++h) ad[h]=ad1[n*NH+h];
  float mx[4]={-1e30f,-1e30f,-1e30f,-1e30f};
  for (int i=s0+t;i<s1;i+=256){
    int eid=eids[i]; int src = eid<NEDGES ? ei_src[eid] : eid-NEDGES;
#pragma unroll
    for (int h=0;h<4;++h){ float v=leaky(as1[src*NH+h]+ad[h]); mx[h]=fmaxf(mx[h],v); }
  }
  red[t]=make_float4(mx[0],mx[1],mx[2],mx[3]); __syncthreads();
  for (int off=128;off>0;off>>=1){
    if (t<off){ float4 a=red[t], b=red[t+off];
      red[t]=make_float4(fmaxf(a.x,b.x),fmaxf(a.y,b.y),fmaxf(a.z,b.z),fmaxf(a.w,b.w)); }
    __syncthreads();
  }
  float4 M4 = red[0]; __syncthreads();
  float mm[4]={M4.x,M4.y,M4.z,M4.w};
  float sm[4]={0.f,0.f,0.f,0.f};
  for (int i=s0+t;i<s1;i+=256){
    int eid=eids[i]; int src = eid<NEDGES ? ei_src[eid] : eid-NEDGES;
#pragma unroll
    for (int h=0;h<4;++h){ float v=leaky(as1[src*NH+h]+ad[h]); sm[h]+=__expf(v-mm[h]); }
  }
  red[t]=make_float4(sm[0],sm[1],sm[2],sm[3]); __syncthreads();
  for (int off=128;off>0;off>>=1){
    if (t<off){ float4 a=red[t], b=red[t+off];
      red[t]=make_float4(a.x+b.x,a.y+b.y,a.z+b.z,a.w+b.w); }
    __syncthreads();
  }
  float4 S4 = red[0];
  float rden[4]={1.f/(S4.x+1e-16f),1.f/(S4.y+1e-16f),1.f/(S4.z+1e-16f),1.f/(S4.w+1e-16f)};
  int w = t>>6, lane = t&63;
  float adw=ad[w], mw=mm[w], rw=rden[w];
  float2 acc = make_float2(0.f,0.f);
  for (int i=s0;i<s1;++i){
    int eid=eids[i]; int src = eid<NEDGES ? ei_src[eid] : eid-NEDGES;
    float v = leaky(as1[src*NH+w]+adw);
    float alpha = __expf(v-mw)*rw;
    float2 hv = *(const float2*)&h1[(size_t)src*HC + w*HIDC + lane*2];
    acc.x += alpha*hv.x; acc.y += alpha*hv.y;
  }
  float2 bb = *(const float2*)&b1[w*HIDC + lane*2];
  *(float2*)&out[(size_t)n*HC + w*HIDC + lane*2] = make_float2(acc.x+bb.x, acc.y+bb.y);
}

// layer-2 attention dots (single head, C=64): 4 nodes per block (1 wave each)
__global__ __launch_bounds__(256) void att2_kernel(const float* __restrict__ h2a,
  const float* __restrict__ att_src, const float* __restrict__ att_dst,
  float* __restrict__ as2, float* __restrict__ ad2)
{
  int t=threadIdx.x; int lane=t&63;
  int n = blockIdx.x*4 + (t>>6);
  float v = h2a[(size_t)n*OUTC + lane];
  float ps = wave_sum(v*att_src[lane]);
  float pd = wave_sum(v*att_dst[lane]);
  if (lane==0){ as2[n]=ps; ad2[n]=pd; }
}

// layer-2 softmax + aggregate + bias + L2-normalize -> z. Block = node, 1 wave.
__global__ __launch_bounds__(64) void agg2_kernel(const float* __restrict__ h2a,
  const float* __restrict__ as2, const float* __restrict__ ad2,
  const int* __restrict__ rowptr, const int* __restrict__ eids, const int* __restrict__ ei_src,
  const float* __restrict__ b2, float* __restrict__ z)
{
  int n = blockIdx.x; int lane = threadIdx.x;
  int s0 = rowptr[n], s1 = rowptr[n+1];
  float adn = ad2[n];
  float mx = -1e30f;
  for (int i=s0+lane;i<s1;i+=64){
    int eid=eids[i]; int src = eid<NEDGES ? ei_src[eid] : eid-NEDGES;
    mx = fmaxf(mx, leaky(as2[src]+adn));
  }
  mx = wave_max(mx);
  float sm = 0.f;
  for (int i=s0+lane;i<s1;i+=64){
    int eid=eids[i]; int src = eid<NEDGES ? ei_src[eid] : eid-NEDGES;
    sm += __expf(leaky(as2[src]+adn)-mx);
  }
  sm = wave_sum(sm);
  float rden = 1.f/(sm+1e-16f);
  float acc = 0.f;
  for (int i=s0;i<s1;++i){
    int eid=eids[i]; int src = eid<NEDGES ? ei_src[eid] : eid-NEDGES;
    float alpha = __expf(leaky(as2[src]+adn)-mx)*rden;
    acc += alpha * h2a[(size_t)src*OUTC + lane];
  }
  float o = acc + b2[lane];
  float nrm2 = wave_sum(o*o);
  float nrm = sqrtf(nrm2);
  z[(size_t)n*OUTC + lane] = o / fmaxf(nrm, 1e-12f);
}

extern "C" void kernel_launch(void* const* d_in, const int* in_sizes, int n_in,
                              void* d_out, int out_size, void* d_ws, size_t ws_size,
                              hipStream_t stream)
{
  const float* x        = (const float*)d_in[0];
  const int*   ei       = (const int*)d_in[1];
  const float* W1       = (const float*)d_in[2];
  const float* att_src1 = (const float*)d_in[3];
  const float* att_dst1 = (const float*)d_in[4];
  const float* b1       = (const float*)d_in[5];
  const float* W2       = (const float*)d_in[6];
  const float* att_src2 = (const float*)d_in[7];
  const float* att_dst2 = (const float*)d_in[8];
  const float* b2       = (const float*)d_in[9];
  const float* Wl       = (const float*)d_in[10];
  const float* bl       = (const float*)d_in[11];
  const int* ei_src = ei;
  const int* ei_dst = ei + NEDGES;

  float* Apred = (float*)d_out;
  float* z     = Apred + (size_t)NNODES*NNODES;
  float* x_    = z + (size_t)NNODES*OUTC;

  // Scratch layout. Total need ~56 MB. If ws_size is too small, carve scratch
  // out of the A_pred region of d_out instead: every intermediate is dead
  // before the final sigmoid(z@z^T) GEMM writes A_pred, and z/x_ live outside
  // that region, so this is chronologically safe.
  const size_t NEED =
      ((size_t)NNODES*HC*4   + 256) +   // h1
      ((size_t)NNODES*HC*4   + 256) +   // h1agg
      ((size_t)NNODES*OUTC*4 + 256) +   // h2a
      ((size_t)NNODES*NH*4   + 256) * 2 +  // as1, ad1
      ((size_t)NNODES*4      + 256) * 2 +  // as2, ad2
      ((size_t)(NNODES+1)*4  + 256) +   // rowptr
      ((size_t)NNODES*4      + 256) * 2 +  // cnt, nxt
      ((size_t)ETOT*4        + 256);    // eids
  char* base = (ws_size >= NEED) ? (char*)d_ws : (char*)Apred;
  size_t o = 0;
  auto alloc = [&](size_t bytes){ void* p = base + o; o += (bytes + 255) & ~(size_t)255; return p; };
  float* h1    = (float*)alloc((size_t)NNODES*HC*4);
  float* h1agg = (float*)alloc((size_t)NNODES*HC*4);
  float* h2a   = (float*)alloc((size_t)NNODES*OUTC*4);
  float* as1   = (float*)alloc((size_t)NNODES*NH*4);
  float* ad1   = (float*)alloc((size_t)NNODES*NH*4);
  float* as2   = (float*)alloc((size_t)NNODES*4);
  float* ad2   = (float*)alloc((size_t)NNODES*4);
  int* rowptr  = (int*)alloc((NNODES+1)*4);
  int* cnt     = (int*)alloc((size_t)NNODES*4);
  int* nxt     = (int*)alloc((size_t)NNODES*4);
  int* eids    = (int*)alloc((size_t)ETOT*4);

  // CSR build (independent of GEMM1)
  zero_ints<<<(NNODES+255)/256,256,0,stream>>>(cnt, NNODES);
  hist_kernel<<<(ETOT+255)/256,256,0,stream>>>(ei_dst, cnt);
  scan_kernel<<<1,1024,0,stream>>>(cnt, rowptr, nxt);
  scatter_kernel<<<(ETOT+255)/256,256,0,stream>>>(ei_dst, nxt, eids);

  // layer 1
  dim3 g1(HC/64, NNODES/64);
  gemm64<0,false><<<g1,256,0,stream>>>(x, W1, nullptr, h1, NNODES, INCH, HC);
  att1_kernel<<<NNODES,256,0,stream>>>(h1, att_src1, att_dst1, as1, ad1);
  agg1_kernel<<<NNODES,256,0,stream>>>(h1, as1, ad1, rowptr, eids, ei_src, b1, h1agg);

  // layer 2
  dim3 g2(OUTC/64, NNODES/64);
  gemm64<0,false><<<g2,256,0,stream>>>(h1agg, W2, nullptr, h2a, NNODES, HC, OUTC);
  att2_kernel<<<NNODES/4,256,0,stream>>>(h2a, att_src2, att_dst2, as2, ad2);
  agg2_kernel<<<NNODES,64,0,stream>>>(h2a, as2, ad2, rowptr, eids, ei_src, b2, z);

  // x_ = elu(z @ Wl + bl)
  dim3 g3(INCH/64, NNODES/64);
  gemm64<2,false><<<g3,256,0,stream>>>(z, Wl, bl, x_, NNODES, OUTC, INCH);

  // A_pred = sigmoid(z @ z^T)
  dim3 g4(NNODES/64, NNODES/64);
  gemm64<3,true><<<g4,256,0,stream>>>(z, z, nullptr, Apred, NNODES, OUTC, NNODES);
}

// Round 3
// 1009.561 us; speedup vs baseline: 1.1747x; 1.1747x over previous
//
#include <hip/hip_runtime.h>
#include <hip/hip_bf16.h>

#define NNODES 12288
#define NEDGES 393216
#define ETOT   (NEDGES + NNODES)
#define INCH   256
#define HIDC   128
#define NH     4
#define HC     512   // NH*HIDC
#define OUTC   64
#define SLOPE  0.2f

typedef __attribute__((ext_vector_type(8))) short bf16x8;
typedef __attribute__((ext_vector_type(4))) float f32x4;

__device__ __forceinline__ float leaky(float v){ return v > 0.f ? v : SLOPE*v; }

__device__ __forceinline__ short bf16cvt(float f){
  union { float f; unsigned u; } x; x.f = f;
  unsigned r = (x.u + 0x7fffu + ((x.u >> 16) & 1u)) >> 16;
  return (short)r;
}

__device__ __forceinline__ float wave_sum(float v){
#pragma unroll
  for (int m=32;m>0;m>>=1) v += __shfl_xor(v, m);
  return v;
}
__device__ __forceinline__ float wave_max(float v){
#pragma unroll
  for (int m=32;m>0;m>>=1) v = fmaxf(v, __shfl_xor(v, m));
  return v;
}

// ---- generic 64x64 tiled fp32 GEMM. M,Nc multiples of 64; K multiple of 16.
// EPI: 0 none, 1 +bias, 2 elu(x+bias), 3 sigmoid(x).  BT: B given as [Nc,K] (use B^T).
template<int EPI, bool BT>
__global__ __launch_bounds__(256) void gemm64(
    const float* __restrict__ A, const float* __restrict__ B,
    const float* __restrict__ bias, float* __restrict__ C,
    int M, int K, int Nc)
{
  __shared__ float As[16][68];
  __shared__ float Bs[16][68];
  int t = threadIdx.x;
  int tx = t & 15, ty = t >> 4;
  int m0 = blockIdx.y * 64, n0 = blockIdx.x * 64;
  float acc[4][4] = {};
  for (int k0 = 0; k0 < K; k0 += 16) {
    {  // A tile: 64 m x 16 k, float4 along k, scatter-transpose into LDS
      int m = t >> 2, kk = (t & 3) << 2;
      const float4 v = *(const float4*)&A[(size_t)(m0+m)*K + k0 + kk];
      As[kk+0][m] = v.x; As[kk+1][m] = v.y; As[kk+2][m] = v.z; As[kk+3][m] = v.w;
    }
    if (!BT) {
      int kk = t >> 4, nn = (t & 15) << 2;
      *(float4*)&Bs[kk][nn] = *(const float4*)&B[(size_t)(k0+kk)*Nc + n0 + nn];
    } else {
      int nn = t >> 2, kk = (t & 3) << 2;
      const float4 v = *(const float4*)&B[(size_t)(n0+nn)*K + k0 + kk];
      Bs[kk+0][nn] = v.x; Bs[kk+1][nn] = v.y; Bs[kk+2][nn] = v.z; Bs[kk+3][nn] = v.w;
    }
    __syncthreads();
#pragma unroll
    for (int kk = 0; kk < 16; ++kk) {
      float4 a = *(const float4*)&As[kk][ty<<2];
      float4 b = *(const float4*)&Bs[kk][tx<<2];
      float av[4]={a.x,a.y,a.z,a.w}, bv[4]={b.x,b.y,b.z,b.w};
#pragma unroll
      for (int i=0;i<4;++i)
#pragma unroll
        for (int j=0;j<4;++j) acc[i][j] += av[i]*bv[j];
    }
    __syncthreads();
  }
#pragma unroll
  for (int i=0;i<4;++i) {
    int row = m0 + (ty<<2) + i;
    int col = n0 + (tx<<2);
    float4 o; float* po = &o.x;
#pragma unroll
    for (int j=0;j<4;++j) {
      float v = acc[i][j];
      if (EPI==1) v += bias[col+j];
      if (EPI==2) { v += bias[col+j]; v = v>0.f ? v : (__expf(v)-1.f); }
      if (EPI==3) { v = 1.f/(1.f+__expf(-v)); }
      po[j]=v;
    }
    *(float4*)&C[(size_t)row*Nc + col] = o;
  }
}

// ---- A_pred = sigmoid(z @ z^T) via bf16 MFMA. z: [NNODES,64] fp32.
// 128x128 tile / block, 4 waves (2x2 of 64x64), K=64 in one stage.
// LDS tiles bf16 [128][64], XOR-swizzled (byte ^= (row&7)<<4) so the
// ds_read_b128 fragment reads are 2-way-conflict-free (free per m136).
__global__ __launch_bounds__(256) void apred_mfma(
    const float* __restrict__ z, float* __restrict__ A)
{
  __shared__ short As[128*64];
  __shared__ short Bs[128*64];
  int t = threadIdx.x;
  int m0 = blockIdx.y * 128, n0 = blockIdx.x * 128;
  // stage both tiles: fp32 global -> bf16 LDS (swizzled)
#pragma unroll
  for (int i = 0; i < 4; ++i) {
    int c = t + 256*i;
    int row = c >> 3, col8 = c & 7;
    int addr = row*128 + ((col8*16) ^ ((row & 7) << 4));
    {
      const float4* p = (const float4*)&z[(size_t)(m0+row)*OUTC + col8*8];
      float4 v0 = p[0], v1 = p[1];
      bf16x8 pk = { bf16cvt(v0.x), bf16cvt(v0.y), bf16cvt(v0.z), bf16cvt(v0.w),
                    bf16cvt(v1.x), bf16cvt(v1.y), bf16cvt(v1.z), bf16cvt(v1.w) };
      *(bf16x8*)((char*)As + addr) = pk;
    }
    {
      const float4* p = (const float4*)&z[(size_t)(n0+row)*OUTC + col8*8];
      float4 v0 = p[0], v1 = p[1];
      bf16x8 pk = { bf16cvt(v0.x), bf16cvt(v0.y), bf16cvt(v0.z), bf16cvt(v0.w),
                    bf16cvt(v1.x), bf16cvt(v1.y), bf16cvt(v1.z), bf16cvt(v1.w) };
      *(bf16x8*)((char*)Bs + addr) = pk;
    }
  }
  __syncthreads();
  int w = t >> 6, lane = t & 63;
  int wr = (w >> 1) * 64, wc = (w & 1) * 64;
  int lr = lane & 15, lk = lane >> 4;
  bf16x8 af[4][2], bf[4][2];
#pragma unroll
  for (int f = 0; f < 4; ++f)
#pragma unroll
    for (int kk = 0; kk < 2; ++kk) {
      int ra = wr + f*16 + lr;
      int rb = wc + f*16 + lr;
      int colb = (kk*64 + lk*16);
      af[f][kk] = *(const bf16x8*)((char*)As + ra*128 + (colb ^ ((ra & 7) << 4)));
      bf[f][kk] = *(const bf16x8*)((char*)Bs + rb*128 + (colb ^ ((rb & 7) << 4)));
    }
  f32x4 acc[4][4];
#pragma unroll
  for (int i=0;i<4;++i)
#pragma unroll
    for (int j=0;j<4;++j) acc[i][j] = (f32x4){0.f,0.f,0.f,0.f};
#pragma unroll
  for (int kk = 0; kk < 2; ++kk)
#pragma unroll
    for (int mi = 0; mi < 4; ++mi)
#pragma unroll
      for (int nj = 0; nj < 4; ++nj)
        acc[mi][nj] = __builtin_amdgcn_mfma_f32_16x16x32_bf16(af[mi][kk], bf[nj][kk], acc[mi][nj], 0, 0, 0);
  // epilogue: C/D layout col=lane&15, row=(lane>>4)*4+reg  [m89]
#pragma unroll
  for (int mi = 0; mi < 4; ++mi)
#pragma unroll
    for (int nj = 0; nj < 4; ++nj) {
      int row = m0 + wr + mi*16 + lk*4;
      int col = n0 + wc + nj*16 + lr;
#pragma unroll
      for (int r = 0; r < 4; ++r) {
        float v = acc[mi][nj][r];
        A[(size_t)(row + r) * NNODES + col] = 1.f/(1.f + __expf(-v));
      }
    }
}

// per-node per-head attention dots for layer 1: block = node, 4 waves = 4 heads
__global__ __launch_bounds__(256) void att1_kernel(
  const float* __restrict__ h1, const float* __restrict__ att_src,
  const float* __restrict__ att_dst, float* __restrict__ as1, float* __restrict__ ad1)
{
  int n = blockIdx.x; int t = threadIdx.x; int h = t>>6, lane = t&63;
  float2 v = *(const float2*)&h1[(size_t)n*HC + h*HIDC + lane*2];
  float2 a = *(const float2*)&att_src[h*HIDC + lane*2];
  float2 b = *(const float2*)&att_dst[h*HIDC + lane*2];
  float ps = wave_sum(v.x*a.x + v.y*a.y);
  float pd = wave_sum(v.x*b.x + v.y*b.y);
  if (lane==0){ as1[n*NH+h]=ps; ad1[n*NH+h]=pd; }
}

__global__ void zero_ints(int* p, int n){ int i=blockIdx.x*256+threadIdx.x; if(i<n) p[i]=0; }

__global__ void hist_kernel(const int* __restrict__ ei_dst, int* __restrict__ cnt){
  int e = blockIdx.x*256+threadIdx.x;
  if (e >= ETOT) return;
  int dst = e < NEDGES ? ei_dst[e] : e - NEDGES;
  atomicAdd(&cnt[dst], 1);
}

__global__ __launch_bounds__(1024) void scan_kernel(const int* __restrict__ cnt,
    int* __restrict__ rowptr, int* __restrict__ nxt){
  __shared__ int part[1024];
  int tid = threadIdx.x;
  int c[12]; int s=0;
  int base = tid*12;
#pragma unroll
  for (int j=0;j<12;++j){ c[j]=cnt[base+j]; s+=c[j]; }
  part[tid]=s; __syncthreads();
  for (int off=1; off<1024; off<<=1){
    int v=0; if (tid>=off) v=part[tid-off];
    __syncthreads();
    part[tid]+=v;
    __syncthreads();
  }
  int run = part[tid]-s;
#pragma unroll
  for (int j=0;j<12;++j){ rowptr[base+j]=run; nxt[base+j]=run; run+=c[j]; }
  if (tid==1023) rowptr[NNODES]=run;
}

__global__ void scatter_kernel(const int* __restrict__ ei_dst, int* __restrict__ nxt,
                               int* __restrict__ eids){
  int e = blockIdx.x*256+threadIdx.x;
  if (e >= ETOT) return;
  int dst = e < NEDGES ? ei_dst[e] : e - NEDGES;
  int pos = atomicAdd(&nxt[dst], 1);
  eids[pos] = e;
}

// layer-1 segment softmax + weighted aggregation. Block = dst node, 256 thr.
__global__ __launch_bounds__(256) void agg1_kernel(
  const float* __restrict__ h1, const float* __restrict__ as1, const float* __restrict__ ad1,
  const int* __restrict__ rowptr, const int* __restrict__ eids, const int* __restrict__ ei_src,
  const float* __restrict__ b1, float* __restrict__ out)
{
  __shared__ float4 red[256];
  int n = blockIdx.x; int t = threadIdx.x;
  int s0 = rowptr[n], s1 = rowptr[n+1];
  float ad[4];
#pragma unroll
  for (int h=0;h<4;++h) ad[h]=ad1[n*NH+h];
  float mx[4]={-1e30f,-1e30f,-1e30f,-1e30f};
  for (int i=s0+t;i<s1;i+=256){
    int eid=eids[i]; int src = eid<NEDGES ? ei_src[eid] : eid-NEDGES;
#pragma unroll
    for (int h=0;h<4;++h){ float v=leaky(as1[src*NH+h]+ad[h]); mx[h]=fmaxf(mx[h],v); }
  }
  red[t]=make_float4(mx[0],mx[1],mx[2],mx[3]); __syncthreads();
  for (int off=128;off>0;off>>=1){
    if (t<off){ float4 a=red[t], b=red[t+off];
      red[t]=make_float4(fmaxf(a.x,b.x),fmaxf(a.y,b.y),fmaxf(a.z,b.z),fmaxf(a.w,b.w)); }
    __syncthreads();
  }
  float4 M4 = red[0]; __syncthreads();
  float mm[4]={M4.x,M4.y,M4.z,M4.w};
  float sm[4]={0.f,0.f,0.f,0.f};
  for (int i=s0+t;i<s1;i+=256){
    int eid=eids[i]; int src = eid<NEDGES ? ei_src[eid] : eid-NEDGES;
#pragma unroll
    for (int h=0;h<4;++h){ float v=leaky(as1[src*NH+h]+ad[h]); sm[h]+=__expf(v-mm[h]); }
  }
  red[t]=make_float4(sm[0],sm[1],sm[2],sm[3]); __syncthreads();
  for (int off=128;off>0;off>>=1){
    if (t<off){ float4 a=red[t], b=red[t+off];
      red[t]=make_float4(a.x+b.x,a.y+b.y,a.z+b.z,a.w+b.w); }
    __syncthreads();
  }
  float4 S4 = red[0];
  float rden[4]={1.f/(S4.x+1e-16f),1.f/(S4.y+1e-16f),1.f/(S4.z+1e-16f),1.f/(S4.w+1e-16f)};
  int w = t>>6, lane = t&63;
  float adw=ad[w], mw=mm[w], rw=rden[w];
  float2 acc = make_float2(0.f,0.f);
  for (int i=s0;i<s1;++i){
    int eid=eids[i]; int src = eid<NEDGES ? ei_src[eid] : eid-NEDGES;
    float v = leaky(as1[src*NH+w]+adw);
    float alpha = __expf(v-mw)*rw;
    float2 hv = *(const float2*)&h1[(size_t)src*HC + w*HIDC + lane*2];
    acc.x += alpha*hv.x; acc.y += alpha*hv.y;
  }
  float2 bb = *(const float2*)&b1[w*HIDC + lane*2];
  *(float2*)&out[(size_t)n*HC + w*HIDC + lane*2] = make_float2(acc.x+bb.x, acc.y+bb.y);
}

// layer-2 attention dots (single head, C=64): 4 nodes per block (1 wave each)
__global__ __launch_bounds__(256) void att2_kernel(const float* __restrict__ h2a,
  const float* __restrict__ att_src, const float* __restrict__ att_dst,
  float* __restrict__ as2, float* __restrict__ ad2)
{
  int t=threadIdx.x; int lane=t&63;
  int n = blockIdx.x*4 + (t>>6);
  float v = h2a[(size_t)n*OUTC + lane];
  float ps = wave_sum(v*att_src[lane]);
  float pd = wave_sum(v*att_dst[lane]);
  if (lane==0){ as2[n]=ps; ad2[n]=pd; }
}

// layer-2 softmax + aggregate + bias + L2-normalize -> z. Block = node, 1 wave.
__global__ __launch_bounds__(64) void agg2_kernel(const float* __restrict__ h2a,
  const float* __restrict__ as2, const float* __restrict__ ad2,
  const int* __restrict__ rowptr, const int* __restrict__ eids, const int* __restrict__ ei_src,
  const float* __restrict__ b2, float* __restrict__ z)
{
  int n = blockIdx.x; int lane = threadIdx.x;
  int s0 = rowptr[n], s1 = rowptr[n+1];
  float adn = ad2[n];
  float mx = -1e30f;
  for (int i=s0+lane;i<s1;i+=64){
    int eid=eids[i]; int src = eid<NEDGES ? ei_src[eid] : eid-NEDGES;
    mx = fmaxf(mx, leaky(as2[src]+adn));
  }
  mx = wave_max(mx);
  float sm = 0.f;
  for (int i=s0+lane;i<s1;i+=64){
    int eid=eids[i]; int src = eid<NEDGES ? ei_src[eid] : eid-NEDGES;
    sm += __expf(leaky(as2[src]+adn)-mx);
  }
  sm = wave_sum(sm);
  float rden = 1.f/(sm+1e-16f);
  float acc = 0.f;
  for (int i=s0;i<s1;++i){
    int eid=eids[i]; int src = eid<NEDGES ? ei_src[eid] : eid-NEDGES;
    float alpha = __expf(leaky(as2[src]+adn)-mx)*rden;
    acc += alpha * h2a[(size_t)src*OUTC + lane];
  }
  float o = acc + b2[lane];
  float nrm2 = wave_sum(o*o);
  float nrm = sqrtf(nrm2);
  z[(size_t)n*OUTC + lane] = o / fmaxf(nrm, 1e-12f);
}

extern "C" void kernel_launch(void* const* d_in, const int* in_sizes, int n_in,
                              void* d_out, int out_size, void* d_ws, size_t ws_size,
                              hipStream_t stream)
{
  const float* x        = (const float*)d_in[0];
  const int*   ei       = (const int*)d_in[1];
  const float* W1       = (const float*)d_in[2];
  const float* att_src1 = (const float*)d_in[3];
  const float* att_dst1 = (const float*)d_in[4];
  const float* b1       = (const float*)d_in[5];
  const float* W2       = (const float*)d_in[6];
  const float* att_src2 = (const float*)d_in[7];
  const float* att_dst2 = (const float*)d_in[8];
  const float* b2       = (const float*)d_in[9];
  const float* Wl       = (const float*)d_in[10];
  const float* bl       = (const float*)d_in[11];
  const int* ei_src = ei;
  const int* ei_dst = ei + NEDGES;

  float* Apred = (float*)d_out;
  float* z     = Apred + (size_t)NNODES*NNODES;
  float* x_    = z + (size_t)NNODES*OUTC;

  // Scratch layout. Total need ~56 MB. If ws_size is too small, carve scratch
  // out of the A_pred region of d_out instead: every intermediate is dead
  // before the final sigmoid(z@z^T) GEMM writes A_pred, and z/x_ live outside
  // that region, so this is chronologically safe.
  const size_t NEED =
      ((size_t)NNODES*HC*4   + 256) +   // h1
      ((size_t)NNODES*HC*4   + 256) +   // h1agg
      ((size_t)NNODES*OUTC*4 + 256) +   // h2a
      ((size_t)NNODES*NH*4   + 256) * 2 +  // as1, ad1
      ((size_t)NNODES*4      + 256) * 2 +  // as2, ad2
      ((size_t)(NNODES+1)*4  + 256) +   // rowptr
      ((size_t)NNODES*4      + 256) * 2 +  // cnt, nxt
      ((size_t)ETOT*4        + 256);    // eids
  char* base = (ws_size >= NEED) ? (char*)d_ws : (char*)Apred;
  size_t o = 0;
  auto alloc = [&](size_t bytes){ void* p = base + o; o += (bytes + 255) & ~(size_t)255; return p; };
  float* h1    = (float*)alloc((size_t)NNODES*HC*4);
  float* h1agg = (float*)alloc((size_t)NNODES*HC*4);
  float* h2a   = (float*)alloc((size_t)NNODES*OUTC*4);
  float* as1   = (float*)alloc((size_t)NNODES*NH*4);
  float* ad1   = (float*)alloc((size_t)NNODES*NH*4);
  float* as2   = (float*)alloc((size_t)NNODES*4);
  float* ad2   = (float*)alloc((size_t)NNODES*4);
  int* rowptr  = (int*)alloc((NNODES+1)*4);
  int* cnt     = (int*)alloc((size_t)NNODES*4);
  int* nxt     = (int*)alloc((size_t)NNODES*4);
  int* eids    = (int*)alloc((size_t)ETOT*4);

  // CSR build (independent of GEMM1)
  zero_ints<<<(NNODES+255)/256,256,0,stream>>>(cnt, NNODES);
  hist_kernel<<<(ETOT+255)/256,256,0,stream>>>(ei_dst, cnt);
  scan_kernel<<<1,1024,0,stream>>>(cnt, rowptr, nxt);
  scatter_kernel<<<(ETOT+255)/256,256,0,stream>>>(ei_dst, nxt, eids);

  // layer 1
  dim3 g1(HC/64, NNODES/64);
  gemm64<0,false><<<g1,256,0,stream>>>(x, W1, nullptr, h1, NNODES, INCH, HC);
  att1_kernel<<<NNODES,256,0,stream>>>(h1, att_src1, att_dst1, as1, ad1);
  agg1_kernel<<<NNODES,256,0,stream>>>(h1, as1, ad1, rowptr, eids, ei_src, b1, h1agg);

  // layer 2
  dim3 g2(OUTC/64, NNODES/64);
  gemm64<0,false><<<g2,256,0,stream>>>(h1agg, W2, nullptr, h2a, NNODES, HC, OUTC);
  att2_kernel<<<NNODES/4,256,0,stream>>>(h2a, att_src2, att_dst2, as2, ad2);
  agg2_kernel<<<NNODES,64,0,stream>>>(h2a, as2, ad2, rowptr, eids, ei_src, b2, z);

  // x_ = elu(z @ Wl + bl)
  dim3 g3(INCH/64, NNODES/64);
  gemm64<2,false><<<g3,256,0,stream>>>(z, Wl, bl, x_, NNODES, OUTC, INCH);

  // A_pred = sigmoid(z @ z^T) via bf16 MFMA, write-bound (~604 MB out)
  dim3 g4(NNODES/128, NNODES/128);
  apred_mfma<<<g4,256,0,stream>>>(z, Apred);
}